// Round 1
// baseline (141.025 us; speedup 1.0000x reference)
//
#include <hip/hip_runtime.h>

#define B_ 2
#define N_ 512
#define C_ 128   // HIDDEN_DIM
#define A_ 64    // ATTN_DIM
#define H_ 128
#define TI 4     // query rows per block in attn kernel

// workspace layout (float offsets)
#define OFF_WOT 0
#define OFF_W1T (OFF_WOT + C_*A_)          // 8192
#define OFF_WYT (OFF_W1T + C_*A_)          // 16384
#define OFF_WET (OFF_WYT + C_*H_)          // 32768
#define OFF_HO  (OFF_WET + A_*H_)          // 40960
#define OFF_H1  (OFF_HO + B_*N_*A_)        // 106496
#define OFF_XY  (OFF_H1 + B_*N_*A_)        // 172032

__device__ __forceinline__ float fast_tanh(float x) {
  // tanh(x) = 1 - 2/(exp(2x)+1)  (algebraically exact; v_exp + v_rcp)
  float e = __expf(x + x);
  return 1.0f - 2.0f * __builtin_amdgcn_rcpf(e + 1.0f);
}

// ---------------- kernel 0: transpose weights into ws ----------------
__global__ __launch_bounds__(256) void prep_weights(
    const float* __restrict__ Wo, const float* __restrict__ W1,
    const float* __restrict__ Wy, const float* __restrict__ We,
    float* __restrict__ ws) {
  int t = blockIdx.x * 256 + threadIdx.x;   // 0..16383
  if (t < A_*C_) {                          // 8192: Wo,W1 [A][C] -> [C][A]; We [H][A] -> [A][H]
    int a = t / C_, c = t % C_;
    ws[OFF_WOT + c*A_ + a] = Wo[t];
    ws[OFF_W1T + c*A_ + a] = W1[t];
    int h2 = t / A_, a2 = t % A_;
    ws[OFF_WET + a2*H_ + h2] = We[t];
  }
  if (t < H_*C_) {                          // 16384: Wy [H][C] -> [C][H]
    int h = t / C_, c = t % C_;
    ws[OFF_WYT + c*H_ + h] = Wy[t];
  }
}

// ---------------- kernel 1: projections h_o, h_1, X_y ----------------
// 4 rows per block; thread t computes one output column for all 4 rows.
__global__ __launch_bounds__(256) void proj_kernel(
    const float* __restrict__ X, const float* __restrict__ by,
    float* __restrict__ ws) {
  __shared__ float xs[4*C_];
  int row0 = blockIdx.x * 4;            // global row in [0, B*N)
  int t = threadIdx.x;
  for (int k = t; k < 4*C_; k += 256) xs[k] = X[(size_t)row0*C_ + k];
  __syncthreads();

  const float* wt;
  int col, stride;
  if (t < 64)       { wt = ws + OFF_WOT; col = t;       stride = A_; }
  else if (t < 128) { wt = ws + OFF_W1T; col = t - 64;  stride = A_; }
  else              { wt = ws + OFF_WYT; col = t - 128; stride = H_; }

  float acc0 = 0.f, acc1 = 0.f, acc2 = 0.f, acc3 = 0.f;
  #pragma unroll 8
  for (int c = 0; c < C_; ++c) {
    float wv = wt[c*stride + col];
    acc0 += xs[0*C_ + c] * wv;
    acc1 += xs[1*C_ + c] * wv;
    acc2 += xs[2*C_ + c] * wv;
    acc3 += xs[3*C_ + c] * wv;
  }
  if (t < 64) {
    float* o = ws + OFF_HO + (size_t)row0*A_ + col;
    o[0] = acc0; o[A_] = acc1; o[2*A_] = acc2; o[3*A_] = acc3;
  } else if (t < 128) {
    float* o = ws + OFF_H1 + (size_t)row0*A_ + col;
    o[0] = acc0; o[A_] = acc1; o[2*A_] = acc2; o[3*A_] = acc3;
  } else {
    float bb = by[col];
    float* o = ws + OFF_XY + (size_t)row0*H_ + col;
    o[0] = acc0 + bb; o[H_] = acc1 + bb; o[2*H_] = acc2 + bb; o[3*H_] = acc3 + bb;
  }
}

// ---------------- kernel 2: attention main ----------------
// 256 blocks (1/CU), 512 threads (8 waves), TI=4 query rows per block.
__global__ __launch_bounds__(512) void attn_kernel(
    const float* __restrict__ Wphi, const float* __restrict__ be,
    const float* __restrict__ ws, float* __restrict__ out) {
  __shared__ float sc[TI][N_];        // scores -> unnormalized softmax p
  __shared__ float redm[TI][8];
  __shared__ float reds[TI][8];
  __shared__ float ebw[TI][8][A_];    // per-wave ebar partials (unnormalized)
  __shared__ float ebar[TI][A_];
  __shared__ float p1s[TI][4][H_];    // part1 partials per j-quarter (unnormalized)
  __shared__ float linv[TI];

  int t = threadIdx.x;
  int w = t >> 6;
  int lane = t & 63;
  int blk = blockIdx.x;               // 0..255
  int b = blk >> 7;
  int i0 = (blk & 127) * TI;

  const float* hog = ws + OFF_HO + (size_t)(b*N_ + i0)*A_;
  const float* h1g = ws + OFF_H1 + (size_t)(b*N_)*A_;
  const float* xyg = ws + OFF_XY + (size_t)(b*N_)*H_;
  const float* wet = ws + OFF_WET;

  float wphi = Wphi[lane];
  float ho0 = hog[0*A_ + lane];
  float ho1 = hog[1*A_ + lane];
  float ho2 = hog[2*A_ + lane];
  float ho3 = hog[3*A_ + lane];

  // ---- Pass A: scores[r][j] = sum_a Wphi[a] * tanh(ho[r][a] + h1[j][a])
  for (int jj = 0; jj < N_/8; ++jj) {
    int j = jj*8 + w;
    float v = h1g[(size_t)j*A_ + lane];
    float p0 = fast_tanh(ho0 + v) * wphi;
    float p1 = fast_tanh(ho1 + v) * wphi;
    float p2 = fast_tanh(ho2 + v) * wphi;
    float p3 = fast_tanh(ho3 + v) * wphi;
    #pragma unroll
    for (int m = 1; m < 64; m <<= 1) {
      p0 += __shfl_xor(p0, m);
      p1 += __shfl_xor(p1, m);
      p2 += __shfl_xor(p2, m);
      p3 += __shfl_xor(p3, m);
    }
    if (lane == 0) { sc[0][j] = p0; sc[1][j] = p1; sc[2][j] = p2; sc[3][j] = p3; }
  }
  __syncthreads();

  // ---- softmax over j (each thread owns one column j = t per row)
  float s0 = sc[0][t], s1 = sc[1][t], s2 = sc[2][t], s3 = sc[3][t];
  float m0 = s0, m1 = s1, m2 = s2, m3 = s3;
  #pragma unroll
  for (int m = 1; m < 64; m <<= 1) {
    m0 = fmaxf(m0, __shfl_xor(m0, m));
    m1 = fmaxf(m1, __shfl_xor(m1, m));
    m2 = fmaxf(m2, __shfl_xor(m2, m));
    m3 = fmaxf(m3, __shfl_xor(m3, m));
  }
  if (lane == 0) { redm[0][w] = m0; redm[1][w] = m1; redm[2][w] = m2; redm[3][w] = m3; }
  __syncthreads();
  m0 = redm[0][0]; m1 = redm[1][0]; m2 = redm[2][0]; m3 = redm[3][0];
  #pragma unroll
  for (int k = 1; k < 8; ++k) {
    m0 = fmaxf(m0, redm[0][k]); m1 = fmaxf(m1, redm[1][k]);
    m2 = fmaxf(m2, redm[2][k]); m3 = fmaxf(m3, redm[3][k]);
  }
  float p0 = __expf(s0 - m0), p1 = __expf(s1 - m1);
  float p2 = __expf(s2 - m2), p3 = __expf(s3 - m3);
  float q0 = p0, q1 = p1, q2 = p2, q3 = p3;
  #pragma unroll
  for (int m = 1; m < 64; m <<= 1) {
    q0 += __shfl_xor(q0, m); q1 += __shfl_xor(q1, m);
    q2 += __shfl_xor(q2, m); q3 += __shfl_xor(q3, m);
  }
  sc[0][t] = p0; sc[1][t] = p1; sc[2][t] = p2; sc[3][t] = p3;
  if (lane == 0) { reds[0][w] = q0; reds[1][w] = q1; reds[2][w] = q2; reds[3][w] = q3; }
  __syncthreads();
  if (t < TI) {
    float l = 0.f;
    #pragma unroll
    for (int k = 0; k < 8; ++k) l += reds[t][k];
    linv[t] = __builtin_amdgcn_rcpf(l);
  }

  // ---- Pass C: ebar[r][a] = sum_j p[r][j] * tanh(ho[r][a] + h1[j][a])  (unnormalized)
  float a0 = 0.f, a1 = 0.f, a2 = 0.f, a3 = 0.f;
  for (int jj = 0; jj < N_/8; ++jj) {
    int j = jj*8 + w;
    float v = h1g[(size_t)j*A_ + lane];
    a0 += sc[0][j] * fast_tanh(ho0 + v);
    a1 += sc[1][j] * fast_tanh(ho1 + v);
    a2 += sc[2][j] * fast_tanh(ho2 + v);
    a3 += sc[3][j] * fast_tanh(ho3 + v);
  }
  ebw[0][w][lane] = a0; ebw[1][w][lane] = a1;
  ebw[2][w][lane] = a2; ebw[3][w][lane] = a3;

  // ---- part1: p1[r][h] = sum_j p[r][j] * Xy[j][h]  (unnormalized)
  {
    int h = t & 127;
    int qd = t >> 7;                      // j-quarter
    float c0 = 0.f, c1 = 0.f, c2 = 0.f, c3 = 0.f;
    const float* xq = xyg + (size_t)(qd*128)*H_ + h;
    for (int jc = 0; jc < 128; ++jc) {
      int j = qd*128 + jc;
      float xv = xq[(size_t)jc*H_];
      c0 += sc[0][j] * xv;
      c1 += sc[1][j] * xv;
      c2 += sc[2][j] * xv;
      c3 += sc[3][j] * xv;
    }
    p1s[0][qd][h] = c0; p1s[1][qd][h] = c1;
    p1s[2][qd][h] = c2; p1s[3][qd][h] = c3;
  }
  __syncthreads();

  // ---- combine per-wave ebar partials
  if (t < TI*A_) {
    int r = t >> 6, a = t & 63;
    float e = 0.f;
    #pragma unroll
    for (int k = 0; k < 8; ++k) e += ebw[r][k][a];
    ebar[r][a] = e;
  }
  __syncthreads();

  // ---- epilogue: out = (part1 + We·ebar) * (1/l) + be
  {
    int hh = t & 127;
    int r = t >> 7;                       // wave-uniform
    float acc = p1s[r][0][hh] + p1s[r][1][hh] + p1s[r][2][hh] + p1s[r][3][hh];
    float e2 = 0.f;
    #pragma unroll 8
    for (int a = 0; a < A_; ++a) e2 += ebar[r][a] * wet[a*H_ + hh];
    out[(size_t)(b*N_ + i0 + r)*H_ + hh] = (acc + e2) * linv[r] + be[hh];
  }
}

extern "C" void kernel_launch(void* const* d_in, const int* in_sizes, int n_in,
                              void* d_out, int out_size, void* d_ws, size_t ws_size,
                              hipStream_t stream) {
  const float* X    = (const float*)d_in[0];
  const float* Wo   = (const float*)d_in[1];
  const float* W1   = (const float*)d_in[2];
  const float* Wphi = (const float*)d_in[3];
  const float* Wy   = (const float*)d_in[4];
  const float* by   = (const float*)d_in[5];
  const float* We   = (const float*)d_in[6];
  const float* be   = (const float*)d_in[7];
  float* out = (float*)d_out;
  float* ws  = (float*)d_ws;

  hipLaunchKernelGGL(prep_weights, dim3(64), dim3(256), 0, stream, Wo, W1, Wy, We, ws);
  hipLaunchKernelGGL(proj_kernel, dim3(B_*N_/4), dim3(256), 0, stream, X, by, ws);
  hipLaunchKernelGGL(attn_kernel, dim3(B_*N_/TI), dim3(512), 0, stream, Wphi, be, ws, out);
}

// Round 2
// 106.506 us; speedup vs baseline: 1.3241x; 1.3241x over previous
//
#include <hip/hip_runtime.h>

#define B_ 2
#define N_ 512
#define C_ 128   // HIDDEN_DIM
#define A_ 64    // ATTN_DIM
#define H_ 128
#define TI 2     // query rows per block in attn kernel

#define SC2L 2.885390081777927f   // 2*log2(e): exp(2x) = 2^(SC2L*x)

// workspace layout (float offsets)
#define OFF_WOT 0
#define OFF_W1T (OFF_WOT + C_*A_)           // 8192
#define OFF_WYT (OFF_W1T + C_*A_)           // 16384
#define OFF_WET (OFF_WYT + C_*H_)           // 32768
#define OFF_HO  (OFF_WET + A_*H_)           // 40960   hoS [g][a], pre-scaled by SC2L
#define OFF_H1S (OFF_HO + B_*N_*A_)         // 106496  h1S [g][a], pre-scaled
#define OFF_H1T (OFF_H1S + B_*N_*A_)        // 172032  h1T [b][a][n], pre-scaled
#define OFF_XY  (OFF_H1T + B_*N_*A_)        // 237568  Xy  [g][h]

__device__ __forceinline__ float fexp2(float x) { return __builtin_amdgcn_exp2f(x); }
__device__ __forceinline__ float frcp(float x)  { return __builtin_amdgcn_rcpf(x); }

// ---------------- kernel 0: transpose weights into ws ----------------
__global__ __launch_bounds__(256) void prep_weights(
    const float* __restrict__ Wo, const float* __restrict__ W1,
    const float* __restrict__ Wy, const float* __restrict__ We,
    float* __restrict__ ws) {
  int t = blockIdx.x * 256 + threadIdx.x;   // 0..16383
  if (t < A_*C_) {                          // Wo,W1 [A][C] -> [C][A]; We [H][A] -> [A][H]
    int a = t / C_, c = t % C_;
    ws[OFF_WOT + c*A_ + a] = Wo[t];
    ws[OFF_W1T + c*A_ + a] = W1[t];
    int h2 = t / A_, a2 = t % A_;
    ws[OFF_WET + a2*H_ + h2] = We[t];
  }
  if (t < H_*C_) {                          // Wy [H][C] -> [C][H]
    int h = t / C_, c = t % C_;
    ws[OFF_WYT + c*H_ + h] = Wy[t];
  }
}

// ---------------- kernel 1: projections (pre-scaled) ----------------
// 4 rows per block; thread t computes one output column for all 4 rows.
__global__ __launch_bounds__(256) void proj_kernel(
    const float* __restrict__ X, const float* __restrict__ by,
    float* __restrict__ ws) {
  __shared__ float xs[4*C_];
  int row0 = blockIdx.x * 4;            // global row in [0, B*N)
  int t = threadIdx.x;
  for (int k = t; k < 4*C_; k += 256) xs[k] = X[(size_t)row0*C_ + k];
  __syncthreads();

  const float* wt;
  int col, stride;
  if (t < 64)       { wt = ws + OFF_WOT; col = t;       stride = A_; }
  else if (t < 128) { wt = ws + OFF_W1T; col = t - 64;  stride = A_; }
  else              { wt = ws + OFF_WYT; col = t - 128; stride = H_; }

  float acc0 = 0.f, acc1 = 0.f, acc2 = 0.f, acc3 = 0.f;
  #pragma unroll 8
  for (int c = 0; c < C_; ++c) {
    float wv = wt[c*stride + col];
    acc0 += xs[0*C_ + c] * wv;
    acc1 += xs[1*C_ + c] * wv;
    acc2 += xs[2*C_ + c] * wv;
    acc3 += xs[3*C_ + c] * wv;
  }
  if (t < 64) {
    float* o = ws + OFF_HO + (size_t)row0*A_ + col;
    o[0] = SC2L*acc0; o[A_] = SC2L*acc1; o[2*A_] = SC2L*acc2; o[3*A_] = SC2L*acc3;
  } else if (t < 128) {
    float* o = ws + OFF_H1S + (size_t)row0*A_ + col;
    o[0] = SC2L*acc0; o[A_] = SC2L*acc1; o[2*A_] = SC2L*acc2; o[3*A_] = SC2L*acc3;
    int b = row0 >> 9, n0 = row0 & (N_-1);
    float* oT = ws + OFF_H1T + (size_t)b*A_*N_ + (size_t)col*N_ + n0;
    oT[0] = SC2L*acc0; oT[1] = SC2L*acc1; oT[2] = SC2L*acc2; oT[3] = SC2L*acc3;
  } else {
    float bb = by[col];
    float* o = ws + OFF_XY + (size_t)row0*H_ + col;
    o[0] = acc0 + bb; o[H_] = acc1 + bb; o[2*H_] = acc2 + bb; o[3*H_] = acc3 + bb;
  }
}

// ---------------- kernel 2: attention main ----------------
// 512 blocks (2/CU), 512 threads (8 waves), TI=2 query rows per block.
__global__ __launch_bounds__(512) void attn_kernel(
    const float* __restrict__ Wphi, const float* __restrict__ be,
    const float* __restrict__ ws, float* __restrict__ out) {
  __shared__ float sc[TI][N_];        // unnormalized softmax p
  __shared__ float redm[TI][8];
  __shared__ float reds[TI][8];
  __shared__ float ebw[TI][8][A_];    // per-wave Σ p·rcp partials
  __shared__ float ebar[TI][A_];      // unnormalized ebar
  __shared__ float p1s[TI][4][H_];    // part1 partials per j-quarter
  __shared__ float hos[TI][A_];       // scaled h_o rows
  __shared__ float wph2[A_];          // 2*Wphi

  int t = threadIdx.x;
  int w = t >> 6;
  int lane = t & 63;
  int blk = blockIdx.x;               // 0..511
  int b = blk >> 8;
  int i0 = (blk & 255) * TI;

  const float* hog = ws + OFF_HO  + (size_t)(b*N_ + i0)*A_;
  const float* h1s = ws + OFF_H1S + (size_t)(b*N_)*A_;
  const float* h1t = ws + OFF_H1T + (size_t)b*A_*N_;
  const float* xyg = ws + OFF_XY  + (size_t)(b*N_)*H_;
  const float* wet = ws + OFF_WET;

  if (t < TI*A_) { int r = t >> 6, a = t & 63; hos[r][a] = hog[r*A_ + a]; }
  if (t < A_)    { float v = Wphi[t]; wph2[t] = v + v; }
  __syncthreads();

  // ---- Pass A: thread t owns j=t. score'[r][j] = -Σ_a wph2[a]·rcp(exp(2x)+1)
  float acc0 = 0.f, acc1 = 0.f;
  #pragma unroll 4
  for (int a = 0; a < A_; ++a) {
    float v = h1t[a*N_ + t];          // scaled h1[j][a]
    float wp = wph2[a];
    float e0 = fexp2(hos[0][a] + v);
    float e1 = fexp2(hos[1][a] + v);
    acc0 = fmaf(wp, frcp(e0 + 1.0f), acc0);
    acc1 = fmaf(wp, frcp(e1 + 1.0f), acc1);
  }
  float s0 = -acc0, s1 = -acc1;

  // ---- softmax over j (thread owns column j = t)
  float m0 = s0, m1 = s1;
  #pragma unroll
  for (int m = 1; m < 64; m <<= 1) {
    m0 = fmaxf(m0, __shfl_xor(m0, m));
    m1 = fmaxf(m1, __shfl_xor(m1, m));
  }
  if (lane == 0) { redm[0][w] = m0; redm[1][w] = m1; }
  __syncthreads();
  m0 = redm[0][0]; m1 = redm[1][0];
  #pragma unroll
  for (int k = 1; k < 8; ++k) { m0 = fmaxf(m0, redm[0][k]); m1 = fmaxf(m1, redm[1][k]); }
  float p0 = __expf(s0 - m0), p1 = __expf(s1 - m1);
  float q0 = p0, q1 = p1;
  #pragma unroll
  for (int m = 1; m < 64; m <<= 1) { q0 += __shfl_xor(q0, m); q1 += __shfl_xor(q1, m); }
  sc[0][t] = p0; sc[1][t] = p1;
  if (lane == 0) { reds[0][w] = q0; reds[1][w] = q1; }
  __syncthreads();
  float l0 = reds[0][0], l1 = reds[1][0];
  #pragma unroll
  for (int k = 1; k < 8; ++k) { l0 += reds[0][k]; l1 += reds[1][k]; }

  // ---- Pass C: lane=a, wave w covers j = jj*8+w. acc_r = Σ_j p[r][j]·rcp
  {
    float ho0r = hos[0][lane], ho1r = hos[1][lane];
    float c0 = 0.f, c1 = 0.f;
    #pragma unroll 4
    for (int jj = 0; jj < N_/8; ++jj) {
      int j = jj*8 + w;
      float v = h1s[(size_t)j*A_ + lane];
      float pj0 = sc[0][j], pj1 = sc[1][j];
      float e0 = fexp2(ho0r + v);
      float e1 = fexp2(ho1r + v);
      c0 = fmaf(pj0, frcp(e0 + 1.0f), c0);
      c1 = fmaf(pj1, frcp(e1 + 1.0f), c1);
    }
    ebw[0][w][lane] = c0; ebw[1][w][lane] = c1;
  }

  // ---- part1: p1[r][h] = Σ_j p[r][j]·Xy[j][h] (unnormalized), j-quarter per thread group
  {
    int h = t & 127;
    int qd = t >> 7;
    float d0 = 0.f, d1 = 0.f;
    const float* xq = xyg + (size_t)(qd*128)*H_ + h;
    #pragma unroll 4
    for (int jc = 0; jc < 128; ++jc) {
      int j = qd*128 + jc;
      float xv = xq[(size_t)jc*H_];
      d0 = fmaf(sc[0][j], xv, d0);
      d1 = fmaf(sc[1][j], xv, d1);
    }
    p1s[0][qd][h] = d0; p1s[1][qd][h] = d1;
  }
  __syncthreads();

  // ---- combine ebar: ebar_un[r][a] = l_r - 2·Σ_w ebw[r][w][a]
  if (t < TI*A_) {
    int r = t >> 6, a = t & 63;
    float e = 0.f;
    #pragma unroll
    for (int k = 0; k < 8; ++k) e += ebw[r][k][a];
    float lr = r ? l1 : l0;
    ebar[r][a] = lr - 2.0f*e;
  }
  __syncthreads();

  // ---- epilogue: out = (part1_un + We·ebar_un)·(1/l) + be
  if (t < TI*H_) {
    int h = t & 127;
    int r = t >> 7;
    float acc = p1s[r][0][h] + p1s[r][1][h] + p1s[r][2][h] + p1s[r][3][h];
    float e2 = 0.f;
    #pragma unroll 8
    for (int a = 0; a < A_; ++a) e2 = fmaf(ebar[r][a], wet[a*H_ + h], e2);
    float lr = r ? l1 : l0;
    out[(size_t)(b*N_ + i0 + r)*H_ + h] = (acc + e2) * frcp(lr) + be[h];
  }
}

extern "C" void kernel_launch(void* const* d_in, const int* in_sizes, int n_in,
                              void* d_out, int out_size, void* d_ws, size_t ws_size,
                              hipStream_t stream) {
  const float* X    = (const float*)d_in[0];
  const float* Wo   = (const float*)d_in[1];
  const float* W1   = (const float*)d_in[2];
  const float* Wphi = (const float*)d_in[3];
  const float* Wy   = (const float*)d_in[4];
  const float* by   = (const float*)d_in[5];
  const float* We   = (const float*)d_in[6];
  const float* be   = (const float*)d_in[7];
  float* out = (float*)d_out;
  float* ws  = (float*)d_ws;

  hipLaunchKernelGGL(prep_weights, dim3(64), dim3(256), 0, stream, Wo, W1, Wy, We, ws);
  hipLaunchKernelGGL(proj_kernel, dim3(B_*N_/4), dim3(256), 0, stream, X, by, ws);
  hipLaunchKernelGGL(attn_kernel, dim3(B_*N_/TI), dim3(512), 0, stream, Wphi, be, ws, out);
}

// Round 3
// 103.212 us; speedup vs baseline: 1.3664x; 1.0319x over previous
//
#include <hip/hip_runtime.h>

#define B_ 2
#define N_ 512
#define C_ 128   // HIDDEN_DIM
#define A_ 64    // ATTN_DIM
#define H_ 128
#define TI 2     // query rows per block in attn kernel

#define SC2L 2.885390081777927f   // 2*log2(e)

// workspace layout (float offsets)
#define OFF_WOT 0
#define OFF_W1T (OFF_WOT + C_*A_)           // 8192
#define OFF_WYT (OFF_W1T + C_*A_)           // 16384
#define OFF_WET (OFF_WYT + C_*H_)           // 32768
#define OFF_TO  (OFF_WET + A_*H_)           // 40960   tanh(h_o) [g][a]
#define OFF_T1S (OFF_TO + B_*N_*A_)         // 106496  tanh(h_1) [g][a]
#define OFF_T1T (OFF_T1S + B_*N_*A_)        // 172032  tanh(h_1) [b][a][n]
#define OFF_XY  (OFF_T1T + B_*N_*A_)        // 237568  Xy [g][h]

__device__ __forceinline__ float fexp2(float x) { return __builtin_amdgcn_exp2f(x); }
__device__ __forceinline__ float frcp(float x)  { return __builtin_amdgcn_rcpf(x); }
__device__ __forceinline__ float ftanh(float x) {
  // tanh(x) = 1 - 2/(exp(2x)+1)
  return 1.0f - 2.0f * frcp(fexp2(SC2L * x) + 1.0f);
}

// ---------------- kernel 0: transpose weights into ws ----------------
__global__ __launch_bounds__(256) void prep_weights(
    const float* __restrict__ Wo, const float* __restrict__ W1,
    const float* __restrict__ Wy, const float* __restrict__ We,
    float* __restrict__ ws) {
  int t = blockIdx.x * 256 + threadIdx.x;   // 0..16383
  if (t < A_*C_) {                          // Wo,W1 [A][C] -> [C][A]; We [H][A] -> [A][H]
    int a = t / C_, c = t % C_;
    ws[OFF_WOT + c*A_ + a] = Wo[t];
    ws[OFF_W1T + c*A_ + a] = W1[t];
    int h2 = t / A_, a2 = t % A_;
    ws[OFF_WET + a2*H_ + h2] = We[t];
  }
  if (t < H_*C_) {                          // Wy [H][C] -> [C][H]
    int h = t / C_, c = t % C_;
    ws[OFF_WYT + c*H_ + h] = Wy[t];
  }
}

// ---------------- kernel 1: projections + tanh ----------------
// 2 rows per block (512 blocks, 2/CU); thread t computes one output column.
__global__ __launch_bounds__(256) void proj_kernel(
    const float* __restrict__ X, const float* __restrict__ by,
    float* __restrict__ ws) {
  __shared__ float xs[2*C_];
  int row0 = blockIdx.x * 2;            // global row in [0, B*N)
  int t = threadIdx.x;
  if (t < 2*C_) xs[t] = X[(size_t)row0*C_ + t];
  __syncthreads();

  const float* wt;
  int col, stride;
  if (t < 64)       { wt = ws + OFF_WOT; col = t;       stride = A_; }
  else if (t < 128) { wt = ws + OFF_W1T; col = t - 64;  stride = A_; }
  else              { wt = ws + OFF_WYT; col = t - 128; stride = H_; }

  float acc0 = 0.f, acc1 = 0.f;
  #pragma unroll 8
  for (int c = 0; c < C_; ++c) {
    float wv = wt[c*stride + col];
    acc0 = fmaf(xs[c], wv, acc0);
    acc1 = fmaf(xs[C_ + c], wv, acc1);
  }
  if (t < 64) {
    float* o = ws + OFF_TO + (size_t)row0*A_ + col;
    o[0] = ftanh(acc0); o[A_] = ftanh(acc1);
  } else if (t < 128) {
    float t0 = ftanh(acc0), t1 = ftanh(acc1);
    float* o = ws + OFF_T1S + (size_t)row0*A_ + col;
    o[0] = t0; o[A_] = t1;
    int b = row0 >> 9, n0 = row0 & (N_-1);
    float* oT = ws + OFF_T1T + (size_t)b*A_*N_ + (size_t)col*N_ + n0;
    oT[0] = t0; oT[1] = t1;
  } else {
    float bb = by[col];
    float* o = ws + OFF_XY + (size_t)row0*H_ + col;
    o[0] = acc0 + bb; o[H_] = acc1 + bb;
  }
}

// ---------------- kernel 2: attention main ----------------
// 512 blocks (2/CU), 512 threads (8 waves), TI=2 query rows per block.
// tanh(ho+h1) = (to + tb) * rcp(1 + to*tb)  -- one trans op per element.
__global__ __launch_bounds__(512) void attn_kernel(
    const float* __restrict__ Wphi, const float* __restrict__ be,
    const float* __restrict__ ws, float* __restrict__ out) {
  __shared__ float sc[TI][N_];        // unnormalized softmax p
  __shared__ float redm[TI][8];
  __shared__ float reds[TI][8];
  __shared__ float ebw[TI][8][A_];    // per-wave ebar partials
  __shared__ float ebar[TI][A_];      // unnormalized ebar
  __shared__ float p1s[TI][4][H_];    // part1 partials per j-quarter
  __shared__ float4 pk[A_];           // {to0, to1, wph*to0, wph*to1}
  __shared__ float wphs[A_];

  int t = threadIdx.x;
  int w = t >> 6;
  int lane = t & 63;
  int blk = blockIdx.x;               // 0..511
  int b = blk >> 8;
  int i0 = (blk & 255) * TI;

  const float* tog = ws + OFF_TO  + (size_t)(b*N_ + i0)*A_;
  const float* t1s = ws + OFF_T1S + (size_t)(b*N_)*A_;
  const float* t1t = ws + OFF_T1T + (size_t)b*A_*N_;
  const float* xyg = ws + OFF_XY  + (size_t)(b*N_)*H_;
  const float* wet = ws + OFF_WET;

  if (t < A_) {
    float wv = Wphi[t];
    float to0 = tog[t], to1 = tog[A_ + t];
    pk[t] = make_float4(to0, to1, wv*to0, wv*to1);
    wphs[t] = wv;
  }
  __syncthreads();

  // ---- Pass A: thread owns j = t.  s_r = Σ_a wph·(to_r+tb)·rcp(1+to_r·tb)
  float s0 = 0.f, s1 = 0.f;
  {
    const float* t1p = t1t + t;
    #pragma unroll 4
    for (int a = 0; a < A_; ++a) {
      float tb = t1p[(size_t)a*N_];
      float4 k = pk[a];
      float wtb = wphs[a] * tb;
      float den0 = fmaf(k.x, tb, 1.0f);
      float den1 = fmaf(k.y, tb, 1.0f);
      float num0 = k.z + wtb;
      float num1 = k.w + wtb;
      s0 = fmaf(num0, frcp(den0), s0);
      s1 = fmaf(num1, frcp(den1), s1);
    }
  }

  // ---- softmax over j (thread owns column j = t)
  float m0 = s0, m1 = s1;
  #pragma unroll
  for (int m = 1; m < 64; m <<= 1) {
    m0 = fmaxf(m0, __shfl_xor(m0, m));
    m1 = fmaxf(m1, __shfl_xor(m1, m));
  }
  if (lane == 0) { redm[0][w] = m0; redm[1][w] = m1; }
  __syncthreads();
  m0 = redm[0][0]; m1 = redm[1][0];
  #pragma unroll
  for (int k = 1; k < 8; ++k) { m0 = fmaxf(m0, redm[0][k]); m1 = fmaxf(m1, redm[1][k]); }
  float p0 = __expf(s0 - m0), p1 = __expf(s1 - m1);
  float q0 = p0, q1 = p1;
  #pragma unroll
  for (int m = 1; m < 64; m <<= 1) { q0 += __shfl_xor(q0, m); q1 += __shfl_xor(q1, m); }
  sc[0][t] = p0; sc[1][t] = p1;
  if (lane == 0) { reds[0][w] = q0; reds[1][w] = q1; }
  __syncthreads();
  float l0 = reds[0][0], l1 = reds[1][0];
  #pragma unroll
  for (int k = 1; k < 8; ++k) { l0 += reds[0][k]; l1 += reds[1][k]; }

  // ---- Pass C: lane = a, wave w covers j = jj*8+w.  c_r = Σ_j p_r·tanh
  {
    float4 kk = pk[lane];
    float to0 = kk.x, to1 = kk.y;
    float c0 = 0.f, c1 = 0.f;
    #pragma unroll 4
    for (int jj = 0; jj < N_/8; ++jj) {
      int j = jj*8 + w;
      float tb = t1s[(size_t)j*A_ + lane];
      float pj0 = sc[0][j], pj1 = sc[1][j];
      float den0 = fmaf(to0, tb, 1.0f);
      float den1 = fmaf(to1, tb, 1.0f);
      float num0 = to0 + tb;
      float num1 = to1 + tb;
      c0 = fmaf(pj0*num0, frcp(den0), c0);
      c1 = fmaf(pj1*num1, frcp(den1), c1);
    }
    ebw[0][w][lane] = c0; ebw[1][w][lane] = c1;
  }

  // ---- part1: p1[r][h] = Σ_j p[r][j]·Xy[j][h] (unnormalized)
  {
    int h = t & 127;
    int qd = t >> 7;
    float d0 = 0.f, d1 = 0.f;
    const float* xq = xyg + (size_t)(qd*128)*H_ + h;
    #pragma unroll 4
    for (int jc = 0; jc < 128; ++jc) {
      int j = qd*128 + jc;
      float xv = xq[(size_t)jc*H_];
      d0 = fmaf(sc[0][j], xv, d0);
      d1 = fmaf(sc[1][j], xv, d1);
    }
    p1s[0][qd][h] = d0; p1s[1][qd][h] = d1;
  }
  __syncthreads();

  // ---- combine ebar partials
  if (t < TI*A_) {
    int r = t >> 6, a = t & 63;
    float e = 0.f;
    #pragma unroll
    for (int k = 0; k < 8; ++k) e += ebw[r][k][a];
    ebar[r][a] = e;
  }
  __syncthreads();

  // ---- epilogue: out = (part1_un + We·ebar_un)·(1/l) + be
  if (t < TI*H_) {
    int h = t & 127;
    int r = t >> 7;
    float acc = p1s[r][0][h] + p1s[r][1][h] + p1s[r][2][h] + p1s[r][3][h];
    float e2 = 0.f;
    #pragma unroll 8
    for (int a = 0; a < A_; ++a) e2 = fmaf(ebar[r][a], wet[a*H_ + h], e2);
    float lr = r ? l1 : l0;
    out[(size_t)(b*N_ + i0 + r)*H_ + h] = (acc + e2) * frcp(lr) + be[h];
  }
}

extern "C" void kernel_launch(void* const* d_in, const int* in_sizes, int n_in,
                              void* d_out, int out_size, void* d_ws, size_t ws_size,
                              hipStream_t stream) {
  const float* X    = (const float*)d_in[0];
  const float* Wo   = (const float*)d_in[1];
  const float* W1   = (const float*)d_in[2];
  const float* Wphi = (const float*)d_in[3];
  const float* Wy   = (const float*)d_in[4];
  const float* by   = (const float*)d_in[5];
  const float* We   = (const float*)d_in[6];
  const float* be   = (const float*)d_in[7];
  float* out = (float*)d_out;
  float* ws  = (float*)d_ws;

  hipLaunchKernelGGL(prep_weights, dim3(64), dim3(256), 0, stream, Wo, W1, Wy, We, ws);
  hipLaunchKernelGGL(proj_kernel, dim3(B_*N_/2), dim3(256), 0, stream, X, by, ws);
  hipLaunchKernelGGL(attn_kernel, dim3(B_*N_/TI), dim3(512), 0, stream, Wphi, be, ws, out);
}